// Round 1
// baseline (15294.792 us; speedup 1.0000x reference)
//
#include <hip/hip_runtime.h>

constexpr int B = 2, S = 1024, D = 512, H = 8, F = 3072, TOPK = 64;

// ================= tiled f32 GEMM =================
// C[M,N] (+)= A[M,K] * B(, optionally B[N,K] transposed-access), row-major.
// BM=128, BN=64, BK=16, 256 threads, 8x4 per-thread microtile.
// CAUSAL: A is lower-triangular in (row, k) -> skip k-tiles beyond bm+BM.
// MASKED: C[r,c] *= mask[r*N+c] before store (no accum).
template<bool TRANSB, bool ACCUM, bool CAUSAL, bool MASKED>
__global__ __launch_bounds__(256) void gemm_f32(
    const float* __restrict__ A, const float* __restrict__ Bm,
    float* __restrict__ C, const float* __restrict__ mask,
    int M, int N, int K, int lda, int ldb, int ldc,
    long sA, long sB, long sC)
{
  constexpr int BM = 128, BN = 64, BK = 16;
  __shared__ float As[BK][BM + 4];   // transposed A tile; +4 keeps f4 alignment
  __shared__ float Bs[BK][BN + 4];
  A  += (long)blockIdx.z * sA;
  Bm += (long)blockIdx.z * sB;
  C  += (long)blockIdx.z * sC;
  const int bm = blockIdx.y * BM, bn = blockIdx.x * BN;
  const int tid = threadIdx.x;
  const int tx = tid & 15, ty = tid >> 4;
  float acc[8][4] = {};
  const int kmax = CAUSAL ? min(K, bm + BM) : K;
  for (int k0 = 0; k0 < kmax; k0 += BK) {
    // A tile: 128x16 floats = 512 float4, 2 per thread; store transposed.
#pragma unroll
    for (int l = 0; l < 2; ++l) {
      const int idx = tid + l * 256;
      const int m = idx >> 2;
      const int kc = (idx & 3) << 2;
      const float4 v = *(const float4*)(A + (long)(bm + m) * lda + (k0 + kc));
      As[kc + 0][m] = v.x; As[kc + 1][m] = v.y;
      As[kc + 2][m] = v.z; As[kc + 3][m] = v.w;
    }
    if (!TRANSB) {
      // B[k][n] tile: 16x64 = 256 float4, 1 per thread, contiguous in LDS.
      const int kk = tid >> 4;
      const int nc = (tid & 15) << 2;
      const float4 v = *(const float4*)(Bm + (long)(k0 + kk) * ldb + (bn + nc));
      *(float4*)&Bs[kk][nc] = v;
    } else {
      // B[n][k] tile: 64x16 = 256 float4, store transposed.
      const int n = tid >> 2;
      const int kc = (tid & 3) << 2;
      const float4 v = *(const float4*)(Bm + (long)(bn + n) * ldb + (k0 + kc));
      Bs[kc + 0][n] = v.x; Bs[kc + 1][n] = v.y;
      Bs[kc + 2][n] = v.z; Bs[kc + 3][n] = v.w;
    }
    __syncthreads();
#pragma unroll
    for (int kk = 0; kk < BK; ++kk) {
      const float4 a0 = *(const float4*)&As[kk][ty * 8];
      const float4 a1 = *(const float4*)&As[kk][ty * 8 + 4];
      const float4 b0 = *(const float4*)&Bs[kk][tx * 4];
      const float av[8] = {a0.x, a0.y, a0.z, a0.w, a1.x, a1.y, a1.z, a1.w};
      const float bv[4] = {b0.x, b0.y, b0.z, b0.w};
#pragma unroll
      for (int i = 0; i < 8; ++i)
#pragma unroll
        for (int j = 0; j < 4; ++j)
          acc[i][j] = fmaf(av[i], bv[j], acc[i][j]);
    }
    __syncthreads();
  }
#pragma unroll
  for (int i = 0; i < 8; ++i) {
    const int r = bm + ty * 8 + i;
    float* cp = C + (long)r * ldc + bn + tx * 4;
    float4 v = make_float4(acc[i][0], acc[i][1], acc[i][2], acc[i][3]);
    if (MASKED) {
      const float* mp = mask + (long)r * N + bn + tx * 4;
      v.x *= mp[0]; v.y *= mp[1]; v.z *= mp[2]; v.w *= mp[3];
    }
    if (ACCUM) {
      const float4 o = *(const float4*)cp;
      v.x += o.x; v.y += o.y; v.z += o.z; v.w += o.w;
    }
    *(float4*)cp = v;
  }
}

// ================= small kernels =================
__global__ void div_rows(const float* __restrict__ x, const float* __restrict__ ln,
                         float* __restrict__ y, int n, int rowlen) {
  for (int i = blockIdx.x * blockDim.x + threadIdx.x; i < n;
       i += gridDim.x * blockDim.x)
    y[i] = x[i] / ln[i / rowlen];
}

__global__ void approx_init_k(float* __restrict__ approx,
                              const float* __restrict__ bias0,
                              const float* __restrict__ evec,
                              const float* __restrict__ ln, int n) {
  for (int i = blockIdx.x * blockDim.x + threadIdx.x; i < n;
       i += gridDim.x * blockDim.x) {
    const int row = i / F;
    const int f = i - row * F;
    approx[i] = bias0[f] + evec[f] / ln[row];
  }
}

// ctmp[h*D+o] = sum_i W_OV[h,i,o] * (ub1[i]+ub2[i])
__global__ void cvec_partial(const float* __restrict__ W_OV,
                             const float* __restrict__ ub1,
                             const float* __restrict__ ub2,
                             float* __restrict__ ctmp) {
  const int o = blockIdx.x * 256 + threadIdx.x;
  const int h = blockIdx.y;
  const float* W = W_OV + (long)h * D * D;
  float acc = 0.f;
  for (int i = 0; i < D; ++i)
    acc = fmaf(W[(long)i * D + o], ub1[i] + ub2[i], acc);
  ctmp[h * D + o] = acc;
}

__global__ void cvec_reduce(const float* __restrict__ ctmp, float* __restrict__ cvec) {
  const int o = blockIdx.x * blockDim.x + threadIdx.x;
  if (o < D) {
    float a = 0.f;
    for (int h = 0; h < H; ++h) a += ctmp[h * D + o];
    cvec[o] = a;
  }
}

// one wave per f: bias0[f] = enc_w[f,:].(b_O - b_dec) + enc_b[f]; evec[f] = enc_w[f,:].cvec
__global__ __launch_bounds__(64) void bias_vec(
    const float* __restrict__ enc_w, const float* __restrict__ b_O,
    const float* __restrict__ b_dec, const float* __restrict__ enc_b,
    const float* __restrict__ cvec, float* __restrict__ bias0,
    float* __restrict__ evec) {
  const int f = blockIdx.x;
  const int l = threadIdx.x;
  float s1 = 0.f, s2 = 0.f;
  for (int o = l; o < D; o += 64) {
    const float w = enc_w[(long)f * D + o];
    s1 = fmaf(w, b_O[o] - b_dec[o], s1);
    s2 = fmaf(w, cvec[o], s2);
  }
  for (int off = 32; off > 0; off >>= 1) {
    s1 += __shfl_down(s1, off);
    s2 += __shfl_down(s2, off);
  }
  if (l == 0) { bias0[f] = s1 + enc_b[f]; evec[f] = s2; }
}

// dec_w [D,F] -> dec_wT [F,D]
__global__ __launch_bounds__(256) void transpose_dw(const float* __restrict__ in,
                                                    float* __restrict__ out) {
  __shared__ float t[32][33];
  const int bx = blockIdx.x * 32;  // f
  const int by = blockIdx.y * 32;  // d
  const int x = threadIdx.x & 31, y = threadIdx.x >> 5;
#pragma unroll
  for (int j = 0; j < 4; ++j) {
    const int row = y + j * 8;
    t[row][x] = in[(long)(by + row) * F + bx + x];
  }
  __syncthreads();
#pragma unroll
  for (int j = 0; j < 4; ++j) {
    const int row = y + j * 8;
    out[(long)(bx + row) * D + by + x] = t[x][row];
  }
}

// top-64 of each row of approx[.,F]; relu; scatter into feat; record (v,idx).
// Tie-break: lowest index wins (matches jax.lax.top_k stability).
__global__ __launch_bounds__(256) void topk_scatter(
    const float* __restrict__ approx, float* __restrict__ feat,
    float* __restrict__ topv, int* __restrict__ topi) {
  const int row = blockIdx.x;  // b*S+s
  const float* ap = approx + (long)row * F;
  __shared__ float vals[F];
  __shared__ float rv[256];
  __shared__ int ri[256];
  for (int j = threadIdx.x; j < F; j += 256) vals[j] = ap[j];
  __syncthreads();
  for (int it = 0; it < TOPK; ++it) {
    float best = -3.4e38f;
    int bi = F;
    for (int j = threadIdx.x; j < F; j += 256) {
      const float v = vals[j];
      if (v > best) { best = v; bi = j; }  // strict > keeps lowest index
    }
    rv[threadIdx.x] = best; ri[threadIdx.x] = bi;
    __syncthreads();
    for (int s2 = 128; s2 > 0; s2 >>= 1) {
      if (threadIdx.x < s2) {
        const float ov = rv[threadIdx.x + s2];
        const int oi = ri[threadIdx.x + s2];
        if (ov > rv[threadIdx.x] ||
            (ov == rv[threadIdx.x] && oi < ri[threadIdx.x])) {
          rv[threadIdx.x] = ov; ri[threadIdx.x] = oi;
        }
      }
      __syncthreads();
    }
    if (threadIdx.x == 0) {
      const int idx = ri[0];
      const float v = fmaxf(rv[0], 0.f);
      feat[(long)row * F + idx] = v;
      topv[row * TOPK + it] = v;
      topi[row * TOPK + it] = idx;
      vals[idx] = -3.4e38f;
    }
    __syncthreads();
  }
}

// recon[row,d] = b_dec[d] + sum_j topv[j] * dec_wT[topi[j], d]
__global__ __launch_bounds__(256) void recon_kernel(
    const float* __restrict__ topv, const int* __restrict__ topi,
    const float* __restrict__ dec_wT, const float* __restrict__ b_dec,
    float* __restrict__ recon) {
  const int row = blockIdx.x;
  __shared__ float sv[TOPK];
  __shared__ int si[TOPK];
  if (threadIdx.x < TOPK) {
    sv[threadIdx.x] = topv[row * TOPK + threadIdx.x];
    si[threadIdx.x] = topi[row * TOPK + threadIdx.x];
  }
  __syncthreads();
  const int d0 = threadIdx.x, d1 = threadIdx.x + 256;
  float a0 = b_dec[d0], a1 = b_dec[d1];
  for (int j = 0; j < TOPK; ++j) {
    const float v = sv[j];
    const float* wp = dec_wT + (long)si[j] * D;
    a0 = fmaf(v, wp[d0], a0);
    a1 = fmaf(v, wp[d1], a1);
  }
  recon[(long)row * D + d0] = a0;
  recon[(long)row * D + d1] = a1;
}

// ================= launch =================
extern "C" void kernel_launch(void* const* d_in, const int* in_sizes, int n_in,
                              void* d_out, int out_size, void* d_ws, size_t ws_size,
                              hipStream_t stream) {
  const float* resid = (const float*)d_in[0];
  const float* ln    = (const float*)d_in[1];
  const float* probs = (const float*)d_in[2];
  const float* W_OV  = (const float*)d_in[3];
  const float* b_O   = (const float*)d_in[4];
  const float* enc_w = (const float*)d_in[5];
  const float* enc_b = (const float*)d_in[6];
  const float* b_dec = (const float*)d_in[7];
  const float* dec_w = (const float*)d_in[8];
  const float* up_dec_[2]  = {(const float*)d_in[9], (const float*)d_in[13]};
  const float* up_bdec_[2] = {(const float*)d_in[10], (const float*)d_in[14]};
  const float* pf_[2]      = {(const float*)d_in[11], (const float*)d_in[15]};
  const float* mask_[2]    = {(const float*)d_in[12], (const float*)d_in[16]};

  float* out_feat  = (float*)d_out;
  float* out_recon = out_feat + (size_t)B * S * F;

  float* ws = (float*)d_ws;
  size_t o = 0;
  float* act     = ws + o; o += (size_t)B * S * D;
  float* up_post = ws + o; o += (size_t)B * S * F;
  float* pp      = ws + o; o += (size_t)B * S * F;
  float* approx  = ws + o; o += (size_t)B * S * F;
  float* attn    = ws + o; o += (size_t)B * S * D;   // per-head, both b
  float* Mh      = ws + o; o += (size_t)D * F;       // doubles as E_h [F,D]
  float* vw      = ws + o; o += (size_t)F * F;       // per-head virtual weights
  float* bias0   = ws + o; o += F;
  float* evec    = ws + o; o += F;
  float* cvec    = ws + o; o += D;
  float* ctmp    = ws + o; o += (size_t)H * D;
  float* dec_wT  = ws + o; o += (size_t)F * D;
  float* topv    = ws + o; o += (size_t)B * S * TOPK;
  int*   topi    = (int*)(ws + o); o += (size_t)B * S * TOPK;

  hipMemsetAsync(d_out, 0, sizeof(float) * (size_t)out_size, stream);

  // preliminaries
  div_rows<<<2048, 256, 0, stream>>>(resid, ln, act, B * S * D, D);
  cvec_partial<<<dim3(2, 8), 256, 0, stream>>>(W_OV, up_bdec_[0], up_bdec_[1], ctmp);
  cvec_reduce<<<2, 256, 0, stream>>>(ctmp, cvec);
  bias_vec<<<F, 64, 0, stream>>>(enc_w, b_O, b_dec, enc_b, cvec, bias0, evec);
  approx_init_k<<<2048, 256, 0, stream>>>(approx, bias0, evec, ln, B * S * F);
  transpose_dw<<<dim3(F / 32, D / 32), 256, 0, stream>>>(dec_w, dec_wT);

  // ---- initial contributions: approx[b] += (probs[b,h] @ act[b]) @ M_h ----
  for (int h = 0; h < H; ++h) {
    const float* Wh = W_OV + (size_t)h * D * D;
    // M_h[i,f] = sum_o Wh[i,o] * enc_w[f,o]   (NT)
    gemm_f32<true, false, false, false><<<dim3(F / 64, D / 128, 1), 256, 0, stream>>>(
        Wh, enc_w, Mh, nullptr, D, F, D, D, D, F, 0, 0, 0);
    // attn[b] = probs[b,h] @ act[b]           (NN, causal, batch over b)
    gemm_f32<false, false, true, false><<<dim3(D / 64, S / 128, 2), 256, 0, stream>>>(
        probs + (size_t)h * S * S, act, attn, nullptr, S, D, S, S, D, D,
        (long)H * S * S, (long)S * D, (long)S * D);
    // approx[b] += attn[b] @ M_h              (NN, accum, batch)
    gemm_f32<false, true, false, false><<<dim3(F / 64, S / 128, 2), 256, 0, stream>>>(
        attn, Mh, approx, nullptr, S, F, D, D, F, F,
        (long)S * D, 0L, (long)S * F);
  }

  // ---- upstream pruned contributions ----
  for (int u = 0; u < 2; ++u) {
    div_rows<<<2048, 256, 0, stream>>>(pf_[u], ln, up_post, B * S * F, F);
    for (int h = 0; h < H; ++h) {
      const float* Wh = W_OV + (size_t)h * D * D;
      // E_h[d,i] = sum_o enc_w[d,o] * Wh[i,o]    (NT) -> Mh buffer
      gemm_f32<true, false, false, false><<<dim3(D / 64, F / 128, 1), 256, 0, stream>>>(
          enc_w, Wh, Mh, nullptr, F, D, D, D, D, D, 0, 0, 0);
      // vw[d,u'] = (E_h @ up_dec)[d,u'] * mask   (NN, masked epilogue)
      gemm_f32<false, false, false, true><<<dim3(F / 64, F / 128, 1), 256, 0, stream>>>(
          Mh, up_dec_[u], vw, mask_[u], F, F, D, D, F, F, 0, 0, 0);
      // pp[b] = probs[b,h] @ up_post[b]          (NN, causal, batch)
      gemm_f32<false, false, true, false><<<dim3(F / 64, S / 128, 2), 256, 0, stream>>>(
          probs + (size_t)h * S * S, up_post, pp, nullptr, S, F, S, S, F, F,
          (long)H * S * S, (long)S * F, (long)S * F);
      // approx[b] += pp[b] @ vw^T                (NT, accum, batch)
      gemm_f32<true, true, false, false><<<dim3(F / 64, S / 128, 2), 256, 0, stream>>>(
          pp, vw, approx, nullptr, S, F, F, F, F, F,
          (long)S * F, 0L, (long)S * F);
    }
  }

  // ---- topk + scatter + decode ----
  topk_scatter<<<B * S, 256, 0, stream>>>(approx, out_feat, topv, topi);
  recon_kernel<<<B * S, 256, 0, stream>>>(topv, topi, dec_wT, b_dec, out_recon);
}

// Round 2
// 6443.839 us; speedup vs baseline: 2.3736x; 2.3736x over previous
//
#include <hip/hip_runtime.h>

constexpr int B = 2, S = 1024, D = 512, H = 8, F = 3072, TOPK = 64;

typedef unsigned short u16;
typedef unsigned int u32;
typedef __attribute__((ext_vector_type(8))) short bfrag;    // 8 bf16 (4 VGPR)
typedef __attribute__((ext_vector_type(4))) short hfrag;    // 4 bf16 (2 VGPR)
typedef __attribute__((ext_vector_type(4))) float f32x4;

__device__ __forceinline__ u16 f2bf_rn(float x) {
  u32 u = __float_as_uint(x);
  u32 r = (u + 0x7FFFu + ((u >> 16) & 1u)) >> 16;
  return (u16)r;
}
__device__ __forceinline__ float bf2f(u16 h) {
  return __uint_as_float(((u32)h) << 16);
}

#define GLOAD_LDS16(gp, lp)                                                   \
  __builtin_amdgcn_global_load_lds(                                           \
      (const __attribute__((address_space(1))) u32*)(gp),                     \
      (__attribute__((address_space(3))) u32*)(lp), 16, 0, 0)

// ============ split-bf16 NT MFMA GEMM ============
// C[M,N] (+)= A[M,K] @ Bt[N,K]^T where A ~ Ah+Al, Bt ~ Bh+Bl (bf16 pairs).
// 3-product: AhBh + AhBl + AlBh, f32 accumulation in MFMA.
// 128x128 tile, BK=32, 256 threads (4 waves, 2x2 of 64x64).
// Tiles staged via global_load_lds(16B) with XOR slot-swizzle (slot ^= (row>>1)&3).
// MASK: C *= mask (ld = ldc) before output. OUTPAIR: write bf16 hi/lo pair.

__device__ __forceinline__ void stage_tile(const u16* __restrict__ g, int r0,
                                           int ld, int k0, u16* smem,
                                           int tileBaseBytes, int tid) {
  const int w = tid >> 6, lane = tid & 63;
#pragma unroll
  for (int p = 0; p < 2; ++p) {
    const int slot = w * 128 + p * 64 + lane;
    const int row = slot >> 2, sl = slot & 3;
    const int sdata = sl ^ ((row >> 1) & 3);
    const u16* gp = g + (long)(r0 + row) * ld + k0 + sdata * 8;
    u16* lp = smem + (tileBaseBytes >> 1) + (w * 128 + p * 64) * 8;  // wave-uniform
    GLOAD_LDS16(gp, lp);
  }
}

__device__ __forceinline__ bfrag frag_from(const char* p, int tileBaseBytes,
                                           int row, int g) {
  const int swz = (row >> 1) & 3;
  const int lo = tileBaseBytes + row * 64 + (((g >> 1) ^ swz) << 4) + (g & 1) * 8;
  const int hi = tileBaseBytes + row * 64 + ((((g >> 1) + 2) ^ swz) << 4) + (g & 1) * 8;
  const hfrag a = *(const hfrag*)(p + lo);
  const hfrag b = *(const hfrag*)(p + hi);
  return __builtin_shufflevector(a, b, 0, 1, 2, 3, 4, 5, 6, 7);
}

template<bool ACCUM, bool CAUSAL, bool MASK, bool OUTPAIR>
__global__ __launch_bounds__(256) void gemm_split3(
    const u16* __restrict__ Ah, const u16* __restrict__ Al,
    const u16* __restrict__ Bh, const u16* __restrict__ Bl,
    float* __restrict__ C, u16* __restrict__ Ch, u16* __restrict__ Cl,
    const float* __restrict__ mask,
    int M, int N, int K, int lda, int ldb, int ldc,
    long sA, long sB, long sC)
{
  __shared__ u16 smem[16384];  // 4 tiles x 8 KB = 32 KB
  const int bm = blockIdx.y * 128, bn = blockIdx.x * 128;
  const long aoff = (long)blockIdx.z * sA;
  const long boff = (long)blockIdx.z * sB;
  const long coff = (long)blockIdx.z * sC;
  const int tid = threadIdx.x;
  const int lane = tid & 63, w = tid >> 6;
  const int wr = w >> 1, wc = w & 1;
  const int lg = lane >> 4, lr = lane & 15;

  f32x4 acc[4][4];
#pragma unroll
  for (int i = 0; i < 4; ++i)
#pragma unroll
    for (int j = 0; j < 4; ++j) {
      acc[i][j][0] = 0.f; acc[i][j][1] = 0.f;
      acc[i][j][2] = 0.f; acc[i][j][3] = 0.f;
    }

  const int kmax = CAUSAL ? min(K, bm + 128) : K;
  const u16* Ahp = Ah + aoff; const u16* Alp = Al + aoff;
  const u16* Bhp = Bh + boff; const u16* Blp = Bl + boff;

  for (int k0 = 0; k0 < kmax; k0 += 32) {
    stage_tile(Ahp, bm, lda, k0, smem, 0, tid);
    stage_tile(Alp, bm, lda, k0, smem, 8192, tid);
    stage_tile(Bhp, bn, ldb, k0, smem, 16384, tid);
    stage_tile(Blp, bn, ldb, k0, smem, 24576, tid);
    __syncthreads();
    const char* p = (const char*)smem;
    bfrag ah[4], al4[4], bh4[4], bl4[4];
#pragma unroll
    for (int i = 0; i < 4; ++i) {
      const int rowA = wr * 64 + i * 16 + lr;
      const int rowB = wc * 64 + i * 16 + lr;
      ah[i]  = frag_from(p, 0,     rowA, lg);
      al4[i] = frag_from(p, 8192,  rowA, lg);
      bh4[i] = frag_from(p, 16384, rowB, lg);
      bl4[i] = frag_from(p, 24576, rowB, lg);
    }
#pragma unroll
    for (int i = 0; i < 4; ++i)
#pragma unroll
      for (int j = 0; j < 4; ++j) {
        acc[i][j] = __builtin_amdgcn_mfma_f32_16x16x32_bf16(ah[i],  bh4[j], acc[i][j], 0, 0, 0);
        acc[i][j] = __builtin_amdgcn_mfma_f32_16x16x32_bf16(ah[i],  bl4[j], acc[i][j], 0, 0, 0);
        acc[i][j] = __builtin_amdgcn_mfma_f32_16x16x32_bf16(al4[i], bh4[j], acc[i][j], 0, 0, 0);
      }
    __syncthreads();
  }

  // epilogue: C/D layout col = lane&15, row = (lane>>4)*4 + reg
#pragma unroll
  for (int i = 0; i < 4; ++i)
#pragma unroll
    for (int j = 0; j < 4; ++j)
#pragma unroll
      for (int r = 0; r < 4; ++r) {
        const int row = bm + wr * 64 + i * 16 + lg * 4 + r;
        const int col = bn + wc * 64 + j * 16 + lr;
        float v = acc[i][j][r];
        if (MASK) v *= mask[(long)row * ldc + col];
        const long ci = coff + (long)row * ldc + col;
        if (OUTPAIR) {
          const u16 h = f2bf_rn(v);
          Ch[ci] = h;
          Cl[ci] = f2bf_rn(v - bf2f(h));
        } else if (ACCUM) {
          C[ci] += v;
        } else {
          C[ci] = v;
        }
      }
}

// ================= f32 tiled GEMM (kept for small K=512/causal attn paths) ==
template<bool TRANSB, bool ACCUM, bool CAUSAL, bool MASKED>
__global__ __launch_bounds__(256) void gemm_f32(
    const float* __restrict__ A, const float* __restrict__ Bm,
    float* __restrict__ C, const float* __restrict__ mask,
    int M, int N, int K, int lda, int ldb, int ldc,
    long sA, long sB, long sC)
{
  constexpr int BM = 128, BN = 64, BK = 16;
  __shared__ float As[BK][BM + 4];
  __shared__ float Bs[BK][BN + 4];
  A  += (long)blockIdx.z * sA;
  Bm += (long)blockIdx.z * sB;
  C  += (long)blockIdx.z * sC;
  const int bm = blockIdx.y * BM, bn = blockIdx.x * BN;
  const int tid = threadIdx.x;
  const int tx = tid & 15, ty = tid >> 4;
  float acc[8][4] = {};
  const int kmax = CAUSAL ? min(K, bm + BM) : K;
  for (int k0 = 0; k0 < kmax; k0 += BK) {
#pragma unroll
    for (int l = 0; l < 2; ++l) {
      const int idx = tid + l * 256;
      const int m = idx >> 2;
      const int kc = (idx & 3) << 2;
      const float4 v = *(const float4*)(A + (long)(bm + m) * lda + (k0 + kc));
      As[kc + 0][m] = v.x; As[kc + 1][m] = v.y;
      As[kc + 2][m] = v.z; As[kc + 3][m] = v.w;
    }
    if (!TRANSB) {
      const int kk = tid >> 4;
      const int nc = (tid & 15) << 2;
      const float4 v = *(const float4*)(Bm + (long)(k0 + kk) * ldb + (bn + nc));
      *(float4*)&Bs[kk][nc] = v;
    } else {
      const int n = tid >> 2;
      const int kc = (tid & 3) << 2;
      const float4 v = *(const float4*)(Bm + (long)(bn + n) * ldb + (k0 + kc));
      Bs[kc + 0][n] = v.x; Bs[kc + 1][n] = v.y;
      Bs[kc + 2][n] = v.z; Bs[kc + 3][n] = v.w;
    }
    __syncthreads();
#pragma unroll
    for (int kk = 0; kk < BK; ++kk) {
      const float4 a0 = *(const float4*)&As[kk][ty * 8];
      const float4 a1 = *(const float4*)&As[kk][ty * 8 + 4];
      const float4 b0 = *(const float4*)&Bs[kk][tx * 4];
      const float av[8] = {a0.x, a0.y, a0.z, a0.w, a1.x, a1.y, a1.z, a1.w};
      const float bv[4] = {b0.x, b0.y, b0.z, b0.w};
#pragma unroll
      for (int i = 0; i < 8; ++i)
#pragma unroll
        for (int j = 0; j < 4; ++j)
          acc[i][j] = fmaf(av[i], bv[j], acc[i][j]);
    }
    __syncthreads();
  }
#pragma unroll
  for (int i = 0; i < 8; ++i) {
    const int r = bm + ty * 8 + i;
    float* cp = C + (long)r * ldc + bn + tx * 4;
    float4 v = make_float4(acc[i][0], acc[i][1], acc[i][2], acc[i][3]);
    if (MASKED) {
      const float* mp = mask + (long)r * N + bn + tx * 4;
      v.x *= mp[0]; v.y *= mp[1]; v.z *= mp[2]; v.w *= mp[3];
    }
    if (ACCUM) {
      const float4 o = *(const float4*)cp;
      v.x += o.x; v.y += o.y; v.z += o.z; v.w += o.w;
    }
    *(float4*)cp = v;
  }
}

// ================= small kernels =================
__global__ void div_rows(const float* __restrict__ x, const float* __restrict__ ln,
                         float* __restrict__ y, int n, int rowlen) {
  for (int i = blockIdx.x * blockDim.x + threadIdx.x; i < n;
       i += gridDim.x * blockDim.x)
    y[i] = x[i] / ln[i / rowlen];
}

__global__ void split_pair(const float* __restrict__ in, u16* __restrict__ oh,
                           u16* __restrict__ ol, long n) {
  for (long i = blockIdx.x * (long)blockDim.x + threadIdx.x; i < n;
       i += gridDim.x * (long)blockDim.x) {
    const float x = in[i];
    const u16 h = f2bf_rn(x);
    oh[i] = h;
    ol[i] = f2bf_rn(x - bf2f(h));
  }
}

// out pair [C][R] = transpose of in [R][C], optional per-row divisor (len R)
__global__ __launch_bounds__(256) void transpose_split(
    const float* __restrict__ in, const float* __restrict__ divv,
    u16* __restrict__ oh, u16* __restrict__ ol, int R, int C) {
  __shared__ float t[32][33];
  const int bx = blockIdx.x * 32;  // C dim
  const int by = blockIdx.y * 32;  // R dim
  const int x = threadIdx.x & 31, y = threadIdx.x >> 5;
#pragma unroll
  for (int j = 0; j < 4; ++j) {
    const int r = by + y + j * 8;
    float v = in[(long)r * C + bx + x];
    if (divv) v /= divv[r];
    t[y + j * 8][x] = v;
  }
  __syncthreads();
#pragma unroll
  for (int j = 0; j < 4; ++j) {
    const int c = bx + y + j * 8;
    const float v = t[x][y + j * 8];
    const u16 h = f2bf_rn(v);
    oh[(long)c * R + by + x] = h;
    ol[(long)c * R + by + x] = f2bf_rn(v - bf2f(h));
  }
}

__global__ void approx_init_k(float* __restrict__ approx,
                              const float* __restrict__ bias0,
                              const float* __restrict__ evec,
                              const float* __restrict__ ln, int n) {
  for (int i = blockIdx.x * blockDim.x + threadIdx.x; i < n;
       i += gridDim.x * blockDim.x) {
    const int row = i / F;
    const int f = i - row * F;
    approx[i] = bias0[f] + evec[f] / ln[row];
  }
}

__global__ void cvec_partial(const float* __restrict__ W_OV,
                             const float* __restrict__ ub1,
                             const float* __restrict__ ub2,
                             float* __restrict__ ctmp) {
  const int o = blockIdx.x * 256 + threadIdx.x;
  const int h = blockIdx.y;
  const float* W = W_OV + (long)h * D * D;
  float acc = 0.f;
  for (int i = 0; i < D; ++i)
    acc = fmaf(W[(long)i * D + o], ub1[i] + ub2[i], acc);
  ctmp[h * D + o] = acc;
}

__global__ void cvec_reduce(const float* __restrict__ ctmp, float* __restrict__ cvec) {
  const int o = blockIdx.x * blockDim.x + threadIdx.x;
  if (o < D) {
    float a = 0.f;
    for (int h = 0; h < H; ++h) a += ctmp[h * D + o];
    cvec[o] = a;
  }
}

__global__ __launch_bounds__(64) void bias_vec(
    const float* __restrict__ enc_w, const float* __restrict__ b_O,
    const float* __restrict__ b_dec, const float* __restrict__ enc_b,
    const float* __restrict__ cvec, float* __restrict__ bias0,
    float* __restrict__ evec) {
  const int f = blockIdx.x;
  const int l = threadIdx.x;
  float s1 = 0.f, s2 = 0.f;
  for (int o = l; o < D; o += 64) {
    const float w = enc_w[(long)f * D + o];
    s1 = fmaf(w, b_O[o] - b_dec[o], s1);
    s2 = fmaf(w, cvec[o], s2);
  }
  for (int off = 32; off > 0; off >>= 1) {
    s1 += __shfl_down(s1, off);
    s2 += __shfl_down(s2, off);
  }
  if (l == 0) { bias0[f] = s1 + enc_b[f]; evec[f] = s2; }
}

__global__ __launch_bounds__(256) void transpose_dw(const float* __restrict__ in,
                                                    float* __restrict__ out) {
  __shared__ float t[32][33];
  const int bx = blockIdx.x * 32;
  const int by = blockIdx.y * 32;
  const int x = threadIdx.x & 31, y = threadIdx.x >> 5;
#pragma unroll
  for (int j = 0; j < 4; ++j) {
    const int row = y + j * 8;
    t[row][x] = in[(long)(by + row) * F + bx + x];
  }
  __syncthreads();
#pragma unroll
  for (int j = 0; j < 4; ++j) {
    const int row = y + j * 8;
    out[(long)(bx + row) * D + by + x] = t[x][row];
  }
}

__global__ __launch_bounds__(256) void topk_scatter(
    const float* __restrict__ approx, float* __restrict__ feat,
    float* __restrict__ topv, int* __restrict__ topi) {
  const int row = blockIdx.x;
  const float* ap = approx + (long)row * F;
  __shared__ float vals[F];
  __shared__ float rv[256];
  __shared__ int ri[256];
  for (int j = threadIdx.x; j < F; j += 256) vals[j] = ap[j];
  __syncthreads();
  for (int it = 0; it < TOPK; ++it) {
    float best = -3.4e38f;
    int bi = F;
    for (int j = threadIdx.x; j < F; j += 256) {
      const float v = vals[j];
      if (v > best) { best = v; bi = j; }
    }
    rv[threadIdx.x] = best; ri[threadIdx.x] = bi;
    __syncthreads();
    for (int s2 = 128; s2 > 0; s2 >>= 1) {
      if (threadIdx.x < s2) {
        const float ov = rv[threadIdx.x + s2];
        const int oi = ri[threadIdx.x + s2];
        if (ov > rv[threadIdx.x] ||
            (ov == rv[threadIdx.x] && oi < ri[threadIdx.x])) {
          rv[threadIdx.x] = ov; ri[threadIdx.x] = oi;
        }
      }
      __syncthreads();
    }
    if (threadIdx.x == 0) {
      const int idx = ri[0];
      const float v = fmaxf(rv[0], 0.f);
      feat[(long)row * F + idx] = v;
      topv[row * TOPK + it] = v;
      topi[row * TOPK + it] = idx;
      vals[idx] = -3.4e38f;
    }
    __syncthreads();
  }
}

__global__ __launch_bounds__(256) void recon_kernel(
    const float* __restrict__ topv, const int* __restrict__ topi,
    const float* __restrict__ dec_wT, const float* __restrict__ b_dec,
    float* __restrict__ recon) {
  const int row = blockIdx.x;
  __shared__ float sv[TOPK];
  __shared__ int si[TOPK];
  if (threadIdx.x < TOPK) {
    sv[threadIdx.x] = topv[row * TOPK + threadIdx.x];
    si[threadIdx.x] = topi[row * TOPK + threadIdx.x];
  }
  __syncthreads();
  const int d0 = threadIdx.x, d1 = threadIdx.x + 256;
  float a0 = b_dec[d0], a1 = b_dec[d1];
  for (int j = 0; j < TOPK; ++j) {
    const float v = sv[j];
    const float* wp = dec_wT + (long)si[j] * D;
    a0 = fmaf(v, wp[d0], a0);
    a1 = fmaf(v, wp[d1], a1);
  }
  recon[(long)row * D + d0] = a0;
  recon[(long)row * D + d1] = a1;
}

// ================= launch =================
extern "C" void kernel_launch(void* const* d_in, const int* in_sizes, int n_in,
                              void* d_out, int out_size, void* d_ws, size_t ws_size,
                              hipStream_t stream) {
  const float* resid = (const float*)d_in[0];
  const float* ln    = (const float*)d_in[1];
  const float* probs = (const float*)d_in[2];
  const float* W_OV  = (const float*)d_in[3];
  const float* b_O   = (const float*)d_in[4];
  const float* enc_w = (const float*)d_in[5];
  const float* enc_b = (const float*)d_in[6];
  const float* b_dec = (const float*)d_in[7];
  const float* dec_w = (const float*)d_in[8];
  const float* up_dec_[2]  = {(const float*)d_in[9], (const float*)d_in[13]};
  const float* up_bdec_[2] = {(const float*)d_in[10], (const float*)d_in[14]};
  const float* pf_[2]      = {(const float*)d_in[11], (const float*)d_in[15]};
  const float* mask_[2]    = {(const float*)d_in[12], (const float*)d_in[16]};

  float* out_feat  = (float*)d_out;
  float* out_recon = out_feat + (size_t)B * S * F;

  float* ws = (float*)d_ws;
  size_t o = 0;
  float* act     = ws + o; o += (size_t)B * S * D;        // 1.05M
  float* approx  = ws + o; o += (size_t)B * S * F;        // 6.29M
  float* Ehf     = ws + o; o += (size_t)F * D;            // 1.57M
  float* attnf   = ws + o; o += (size_t)B * S * D;        // 1.05M
  float* dec_wT  = ws + o; o += (size_t)F * D;            // 1.57M
  float* bias0   = ws + o; o += F;
  float* evec    = ws + o; o += F;
  float* cvec    = ws + o; o += D;
  float* ctmp    = ws + o; o += (size_t)H * D;
  float* topv    = ws + o; o += (size_t)B * S * TOPK;
  int*   topi    = (int*)(ws + o); o += (size_t)B * S * TOPK;
  // bf16 pair buffers (counted in f32 slots = n_u16/2)
  u16* upTh = (u16*)(ws + o); o += (size_t)2 * B * F * S / 2;   // [u][b][F][S]
  u16* upTl = (u16*)(ws + o); o += (size_t)2 * B * F * S / 2;
  u16* udTh = (u16*)(ws + o); o += (size_t)2 * F * D / 2;       // [u][F][D]
  u16* udTl = (u16*)(ws + o); o += (size_t)2 * F * D / 2;
  u16* Ph   = (u16*)(ws + o); o += (size_t)B * S * S / 2;       // probs_h pair
  u16* Pl   = (u16*)(ws + o); o += (size_t)B * S * S / 2;
  u16* Ehh  = (u16*)(ws + o); o += (size_t)F * D / 2;
  u16* Ehl  = (u16*)(ws + o); o += (size_t)F * D / 2;
  u16* Ath  = (u16*)(ws + o); o += (size_t)B * S * D / 2;
  u16* Atl  = (u16*)(ws + o); o += (size_t)B * S * D / 2;
  u16* vwh  = (u16*)(ws + o); o += (size_t)F * F / 2;
  u16* vwl  = (u16*)(ws + o); o += (size_t)F * F / 2;
  u16* pph  = (u16*)(ws + o); o += (size_t)B * S * F / 2;
  u16* ppl  = (u16*)(ws + o); o += (size_t)B * S * F / 2;

  hipMemsetAsync(d_out, 0, sizeof(float) * (size_t)out_size, stream);

  // preliminaries
  div_rows<<<2048, 256, 0, stream>>>(resid, ln, act, B * S * D, D);
  cvec_partial<<<dim3(2, 8), 256, 0, stream>>>(W_OV, up_bdec_[0], up_bdec_[1], ctmp);
  cvec_reduce<<<2, 256, 0, stream>>>(ctmp, cvec);
  bias_vec<<<F, 64, 0, stream>>>(enc_w, b_O, b_dec, enc_b, cvec, bias0, evec);
  approx_init_k<<<2048, 256, 0, stream>>>(approx, bias0, evec, ln, B * S * F);
  transpose_dw<<<dim3(F / 32, D / 32), 256, 0, stream>>>(dec_w, dec_wT);

  // upstream transposed+split operands (persistent across heads)
  for (int u = 0; u < 2; ++u) {
    for (int b = 0; b < B; ++b) {
      transpose_split<<<dim3(F / 32, S / 32), 256, 0, stream>>>(
          pf_[u] + (size_t)b * S * F, ln + (size_t)b * S,
          upTh + ((size_t)u * B + b) * F * S, upTl + ((size_t)u * B + b) * F * S,
          S, F);
    }
    transpose_split<<<dim3(F / 32, D / 32), 256, 0, stream>>>(
        up_dec_[u], nullptr, udTh + (size_t)u * F * D, udTl + (size_t)u * F * D,
        D, F);
  }

  for (int h = 0; h < H; ++h) {
    const float* Wh = W_OV + (size_t)h * D * D;
    // probs_h split (per batch)
    for (int b = 0; b < B; ++b)
      split_pair<<<1024, 256, 0, stream>>>(
          probs + ((size_t)b * H + h) * S * S,
          Ph + (size_t)b * S * S, Pl + (size_t)b * S * S, (long)S * S);
    // Eh[f,i] = sum_o enc_w[f,o] * Wh[i,o]  (f32, exact) -> split
    gemm_f32<true, false, false, false><<<dim3(D / 64, F / 128, 1), 256, 0, stream>>>(
        enc_w, Wh, Ehf, nullptr, F, D, D, D, D, D, 0, 0, 0);
    split_pair<<<1024, 256, 0, stream>>>(Ehf, Ehh, Ehl, (long)F * D);
    // attn[b] = probs[b,h] @ act[b]  (f32 causal, exact) -> split
    gemm_f32<false, false, true, false><<<dim3(D / 64, S / 128, B), 256, 0, stream>>>(
        probs + (size_t)h * S * S, act, attnf, nullptr, S, D, S, S, D, D,
        (long)H * S * S, (long)S * D, (long)S * D);
    split_pair<<<1024, 256, 0, stream>>>(attnf, Ath, Atl, (long)B * S * D);
    // approx[b] += attn[b] @ Eh^T   (MFMA split-3, accum f32)
    gemm_split3<true, false, false, false><<<dim3(F / 128, S / 128, B), 256, 0, stream>>>(
        Ath, Atl, Ehh, Ehl, approx, nullptr, nullptr, nullptr,
        S, F, D, D, D, F, (long)S * D, 0L, (long)S * F);

    for (int u = 0; u < 2; ++u) {
      // vw[d,u'] = (Eh @ up_decT^T)[d,u'] * mask  -> bf16 pair
      gemm_split3<false, false, true, true><<<dim3(F / 128, F / 128, 1), 256, 0, stream>>>(
          Ehh, Ehl, udTh + (size_t)u * F * D, udTl + (size_t)u * F * D,
          nullptr, vwh, vwl, mask_[u],
          F, F, D, D, D, F, 0L, 0L, 0L);
      // pp[b] = probs[b,h] @ up_postT^T (causal) -> bf16 pair
      gemm_split3<false, true, false, true><<<dim3(F / 128, S / 128, B), 256, 0, stream>>>(
          Ph, Pl, upTh + (size_t)u * B * F * S, upTl + (size_t)u * B * F * S,
          nullptr, pph, ppl, nullptr,
          S, F, S, S, S, F, (long)S * S, (long)F * S, (long)S * F);
      // approx[b] += pp[b] @ vw^T  (MFMA split-3, accum f32)
      gemm_split3<true, false, false, false><<<dim3(F / 128, S / 128, B), 256, 0, stream>>>(
          pph, ppl, vwh, vwl, approx, nullptr, nullptr, nullptr,
          S, F, F, F, F, F, (long)S * F, 0L, (long)S * F);
    }
  }

  // ---- topk + scatter + decode ----
  topk_scatter<<<B * S, 256, 0, stream>>>(approx, out_feat, topv, topi);
  recon_kernel<<<B * S, 256, 0, stream>>>(topv, topi, dec_wT, b_dec, out_recon);
}

// Round 4
// 4553.119 us; speedup vs baseline: 3.3592x; 1.4153x over previous
//
#include <hip/hip_runtime.h>

constexpr int B = 2, S = 1024, D = 512, H = 8, F = 3072, TOPK = 64;

typedef unsigned short u16;
typedef unsigned int u32;
typedef __attribute__((ext_vector_type(8))) short bfrag;    // 8 bf16 (4 VGPR)
typedef __attribute__((ext_vector_type(4))) float f32x4;

__device__ __forceinline__ u16 f2bf_rn(float x) {
  u32 u = __float_as_uint(x);
  u32 r = (u + 0x7FFFu + ((u >> 16) & 1u)) >> 16;
  return (u16)r;
}
__device__ __forceinline__ float bf2f(u16 h) {
  return __uint_as_float(((u32)h) << 16);
}

#define GLOAD_LDS16(gp, lp)                                                   \
  __builtin_amdgcn_global_load_lds(                                           \
      (const __attribute__((address_space(1))) u32*)(gp),                     \
      (__attribute__((address_space(3))) u32*)(lp), 16, 0, 0)

// ---- stage one 128x32 bf16 tile (8KB) into LDS, granule-swizzled ----
// LDS slot s (16B granules): row = s>>2, slot sl = s&3 holds global k-granule
// sl ^ ((row>>1)&3). Write side linear (gload_lds); permutation applied on the
// per-lane GLOBAL source address (rule 21: both-sides involution).
__device__ __forceinline__ void stage_tile2(const u16* __restrict__ g, int r0,
                                            int ld, int k0, u16* lds,
                                            int w, int lane) {
#pragma unroll
  for (int p = 0; p < 2; ++p) {
    const int slot = w * 128 + p * 64 + lane;
    const int row = slot >> 2, sl = slot & 3;
    const int gr = sl ^ ((row >> 1) & 3);
    const u16* gp = g + (long)(r0 + row) * ld + k0 + gr * 8;
    u16* lp = lds + (w * 128 + p * 64) * 8;  // wave-uniform base; +lane*16B auto
    GLOAD_LDS16(gp, lp);
  }
}

// read fragment: lane group lg holds global k-granule lg of `row`
__device__ __forceinline__ bfrag frag_at(const u16* tile, int row, int lg) {
  const int idx = row * 32 + ((lg ^ ((row >> 1) & 3)) << 3);
  return *(const bfrag*)(tile + idx);
}

// ============ split-bf16 NT MFMA GEMM v2 (unchanged from round 3) ============
// C[M,N] (+)= A[M,K] @ Bt[N,K]^T, operands as bf16 hi/lo pairs.
// 3-product AhBh+AhBl+AlBh, f32 MFMA accum. 128x128 block, BK=32,
// 4 waves (2x2 of 64x64). Double-buffered LDS (64KB), T3 2-phase.
// 1D grid with bijective XCD swizzle; z -> (zb = z%NB, zh = z/NB) offsets.
template<bool ACCUM, bool CAUSAL, bool MASK, bool OUTPAIR>
__global__ __launch_bounds__(256) void gemm_split3(
    const u16* __restrict__ Ah0, const u16* __restrict__ Al0,
    const u16* __restrict__ Bh0, const u16* __restrict__ Bl0,
    float* __restrict__ C, u16* __restrict__ Ch, u16* __restrict__ Cl,
    const float* __restrict__ mask0, const float* __restrict__ mask1, int ldm,
    int K, int lda, int ldb, int ldc, int gx, int gy, int NB,
    long sAb, long sAh, long sBb, long sBh, long sCb, long sCh)
{
  __shared__ u16 smem[32768];  // 2 bufs x 4 tiles x 4096 u16 = 64 KB

  // bijective XCD swizzle (m204)
  const int nwg = gridDim.x;
  const int q = nwg >> 3, r = nwg & 7;
  const int xcd = blockIdx.x & 7, lid = blockIdx.x >> 3;
  const int sw = (xcd < r ? xcd * (q + 1) : r * (q + 1) + (xcd - r) * q) + lid;
  const int gxy = gx * gy;
  const int z = sw / gxy;
  const int rem = sw - z * gxy;
  const int by = rem / gx;
  const int bx = rem - by * gx;
  const int zb = z % NB, zh = z / NB;

  const u16* Ahp = Ah0 + zb * sAb + zh * sAh;
  const u16* Alp = Al0 + zb * sAb + zh * sAh;
  const u16* Bhp = Bh0 + zb * sBb + zh * sBh;
  const u16* Blp = Bl0 + zb * sBb + zh * sBh;
  const long coff = zb * sCb + zh * sCh;

  const int bm = by * 128, bn = bx * 128;
  const int tid = threadIdx.x;
  const int lane = tid & 63, w = tid >> 6;
  const int wr = w >> 1, wc = w & 1;
  const int lg = lane >> 4, lr = lane & 15;

  f32x4 acc[4][4];
#pragma unroll
  for (int i = 0; i < 4; ++i)
#pragma unroll
    for (int j = 0; j < 4; ++j) {
      acc[i][j][0] = 0.f; acc[i][j][1] = 0.f;
      acc[i][j][2] = 0.f; acc[i][j][3] = 0.f;
    }

  const int kmax = CAUSAL ? min(K, bm + 128) : K;
  const int nt = kmax >> 5;

#define STAGE(buf, k0)                                        \
  do {                                                        \
    u16* base_ = smem + (buf) * 16384;                        \
    stage_tile2(Ahp, bm, lda, (k0), base_,         w, lane);  \
    stage_tile2(Alp, bm, lda, (k0), base_ + 4096,  w, lane);  \
    stage_tile2(Bhp, bn, ldb, (k0), base_ + 8192,  w, lane);  \
    stage_tile2(Blp, bn, ldb, (k0), base_ + 12288, w, lane);  \
  } while (0)

  STAGE(0, 0);
  for (int t = 0; t < nt; ++t) {
    const int cur = t & 1;
    __syncthreads();                       // drains prior stage (vmcnt 0)
    if (t + 1 < nt) STAGE(cur ^ 1, (t + 1) << 5);  // overlaps with compute
    const u16* bufp = smem + cur * 16384;
    bfrag ah[4], al4[4], bh4[4], bl4[4];
#pragma unroll
    for (int i = 0; i < 4; ++i) {
      const int rowA = wr * 64 + i * 16 + lr;
      const int rowB = wc * 64 + i * 16 + lr;
      ah[i]  = frag_at(bufp,          rowA, lg);
      al4[i] = frag_at(bufp + 4096,   rowA, lg);
      bh4[i] = frag_at(bufp + 8192,   rowB, lg);
      bl4[i] = frag_at(bufp + 12288,  rowB, lg);
    }
#pragma unroll
    for (int i = 0; i < 4; ++i)
#pragma unroll
      for (int j = 0; j < 4; ++j) {
        acc[i][j] = __builtin_amdgcn_mfma_f32_16x16x32_bf16(ah[i],  bh4[j], acc[i][j], 0, 0, 0);
        acc[i][j] = __builtin_amdgcn_mfma_f32_16x16x32_bf16(ah[i],  bl4[j], acc[i][j], 0, 0, 0);
        acc[i][j] = __builtin_amdgcn_mfma_f32_16x16x32_bf16(al4[i], bh4[j], acc[i][j], 0, 0, 0);
      }
  }
#undef STAGE

  // epilogue: C/D layout col = lane&15, row = (lane>>4)*4 + reg
  const float* mp_ = MASK ? (zh ? mask1 : mask0) : nullptr;
#pragma unroll
  for (int i = 0; i < 4; ++i)
#pragma unroll
    for (int j = 0; j < 4; ++j)
#pragma unroll
      for (int rr = 0; rr < 4; ++rr) {
        const int row = bm + wr * 64 + i * 16 + lg * 4 + rr;
        const int col = bn + wc * 64 + j * 16 + lr;
        float v = acc[i][j][rr];
        if (MASK) v *= mp_[(long)row * ldm + col];
        const long ci = coff + (long)row * ldc + col;
        if (OUTPAIR) {
          const u16 h = f2bf_rn(v);
          Ch[ci] = h;
          Cl[ci] = f2bf_rn(v - bf2f(h));
        } else if (ACCUM) {
          C[ci] += v;
        } else {
          C[ci] = v;
        }
      }
}

// ================= small kernels =================
__global__ void split_pair(const float* __restrict__ in, u16* __restrict__ oh,
                           u16* __restrict__ ol, long n) {
  for (long i = blockIdx.x * (long)blockDim.x + threadIdx.x; i < n;
       i += gridDim.x * (long)blockDim.x) {
    const float x = in[i];
    const u16 h = f2bf_rn(x);
    oh[i] = h;
    ol[i] = f2bf_rn(x - bf2f(h));
  }
}

// out pair [C][R] = transpose of in [R][C], optional per-input-row divisor
__global__ __launch_bounds__(256) void transpose_split(
    const float* __restrict__ in, const float* __restrict__ divv,
    u16* __restrict__ oh, u16* __restrict__ ol, int R, int C) {
  __shared__ float t[32][33];
  const int bx = blockIdx.x * 32;  // C dim
  const int by = blockIdx.y * 32;  // R dim
  const int x = threadIdx.x & 31, y = threadIdx.x >> 5;
#pragma unroll
  for (int j = 0; j < 4; ++j) {
    const int rr = by + y + j * 8;
    float v = in[(long)rr * C + bx + x];
    if (divv) v /= divv[rr];
    t[y + j * 8][x] = v;
  }
  __syncthreads();
#pragma unroll
  for (int j = 0; j < 4; ++j) {
    const int c = bx + y + j * 8;
    const float v = t[x][y + j * 8];
    const u16 h = f2bf_rn(v);
    oh[(long)c * R + by + x] = h;
    ol[(long)c * R + by + x] = f2bf_rn(v - bf2f(h));
  }
}

__global__ void cvec_partial(const float* __restrict__ W_OV,
                             const float* __restrict__ ub1,
                             const float* __restrict__ ub2,
                             float* __restrict__ ctmp) {
  const int o = blockIdx.x * 256 + threadIdx.x;
  const int h = blockIdx.y;
  const float* W = W_OV + (long)h * D * D;
  float acc = 0.f;
  for (int i = 0; i < D; ++i)
    acc = fmaf(W[(long)i * D + o], ub1[i] + ub2[i], acc);
  ctmp[h * D + o] = acc;
}

__global__ void cvec_reduce(const float* __restrict__ ctmp, float* __restrict__ cvec) {
  const int o = blockIdx.x * blockDim.x + threadIdx.x;
  if (o < D) {
    float a = 0.f;
    for (int h = 0; h < H; ++h) a += ctmp[h * D + o];
    cvec[o] = a;
  }
}

__global__ __launch_bounds__(64) void bias_vec(
    const float* __restrict__ enc_w, const float* __restrict__ b_O,
    const float* __restrict__ b_dec, const float* __restrict__ enc_b,
    const float* __restrict__ cvec, float* __restrict__ bias0,
    float* __restrict__ evec) {
  const int f = blockIdx.x;
  const int l = threadIdx.x;
  float s1 = 0.f, s2 = 0.f;
  for (int o = l; o < D; o += 64) {
    const float w = enc_w[(long)f * D + o];
    s1 = fmaf(w, b_O[o] - b_dec[o], s1);
    s2 = fmaf(w, cvec[o], s2);
  }
  for (int off = 32; off > 0; off >>= 1) {
    s1 += __shfl_down(s1, off);
    s2 += __shfl_down(s2, off);
  }
  if (l == 0) { bias0[f] = s1 + enc_b[f]; evec[f] = s2; }
}

__global__ __launch_bounds__(256) void transpose_dw(const float* __restrict__ in,
                                                    float* __restrict__ out) {
  __shared__ float t[32][33];
  const int bx = blockIdx.x * 32;
  const int by = blockIdx.y * 32;
  const int x = threadIdx.x & 31, y = threadIdx.x >> 5;
#pragma unroll
  for (int j = 0; j < 4; ++j) {
    const int row = y + j * 8;
    t[row][x] = in[(long)(by + row) * F + bx + x];
  }
  __syncthreads();
#pragma unroll
  for (int j = 0; j < 4; ++j) {
    const int row = y + j * 8;
    out[(long)(bx + row) * D + by + x] = t[x][row];
  }
}

// top-64 of (bias0 + evec/ln + P) per row; relu; scatter; record.
__global__ __launch_bounds__(256) void topk_fused(
    const float* __restrict__ P, const float* __restrict__ bias0,
    const float* __restrict__ evec, const float* __restrict__ ln,
    float* __restrict__ feat, float* __restrict__ topv, int* __restrict__ topi) {
  const int row = blockIdx.x;  // b*S+s
  const float rln = 1.f / ln[row];
  const float* p0 = P + (long)row * F;
  __shared__ float vals[F];
  __shared__ float rv[256];
  __shared__ int ri[256];
  for (int j = threadIdx.x; j < F; j += 256)
    vals[j] = bias0[j] + evec[j] * rln + p0[j];
  __syncthreads();
  for (int it = 0; it < TOPK; ++it) {
    float best = -3.4e38f;
    int bi = F;
    for (int j = threadIdx.x; j < F; j += 256) {
      const float v = vals[j];
      if (v > best) { best = v; bi = j; }  // strict > keeps lowest index
    }
    rv[threadIdx.x] = best; ri[threadIdx.x] = bi;
    __syncthreads();
    for (int s2 = 128; s2 > 0; s2 >>= 1) {
      if (threadIdx.x < s2) {
        const float ov = rv[threadIdx.x + s2];
        const int oi = ri[threadIdx.x + s2];
        if (ov > rv[threadIdx.x] ||
            (ov == rv[threadIdx.x] && oi < ri[threadIdx.x])) {
          rv[threadIdx.x] = ov; ri[threadIdx.x] = oi;
        }
      }
      __syncthreads();
    }
    if (threadIdx.x == 0) {
      const int idx = ri[0];
      const float v = fmaxf(rv[0], 0.f);
      feat[(long)row * F + idx] = v;
      topv[row * TOPK + it] = v;
      topi[row * TOPK + it] = idx;
      vals[idx] = -3.4e38f;
    }
    __syncthreads();
  }
}

__global__ __launch_bounds__(256) void recon_kernel(
    const float* __restrict__ topv, const int* __restrict__ topi,
    const float* __restrict__ dec_wT, const float* __restrict__ b_dec,
    float* __restrict__ recon) {
  const int row = blockIdx.x;
  __shared__ float sv[TOPK];
  __shared__ int si[TOPK];
  if (threadIdx.x < TOPK) {
    sv[threadIdx.x] = topv[row * TOPK + threadIdx.x];
    si[threadIdx.x] = topi[row * TOPK + threadIdx.x];
  }
  __syncthreads();
  const int d0 = threadIdx.x, d1 = threadIdx.x + 256;
  float a0 = b_dec[d0], a1 = b_dec[d1];
  for (int j = 0; j < TOPK; ++j) {
    const float v = sv[j];
    const float* wp = dec_wT + (long)si[j] * D;
    a0 = fmaf(v, wp[d0], a0);
    a1 = fmaf(v, wp[d1], a1);
  }
  recon[(long)row * D + d0] = a0;
  recon[(long)row * D + d1] = a1;
}

// ================= launch =================
extern "C" void kernel_launch(void* const* d_in, const int* in_sizes, int n_in,
                              void* d_out, int out_size, void* d_ws, size_t ws_size,
                              hipStream_t stream) {
  const float* resid = (const float*)d_in[0];
  const float* ln    = (const float*)d_in[1];
  const float* probs = (const float*)d_in[2];
  const float* W_OV  = (const float*)d_in[3];
  const float* b_O   = (const float*)d_in[4];
  const float* enc_w = (const float*)d_in[5];
  const float* enc_b = (const float*)d_in[6];
  const float* b_dec = (const float*)d_in[7];
  const float* dec_w = (const float*)d_in[8];
  const float* up_dec_[2]  = {(const float*)d_in[9], (const float*)d_in[13]};
  const float* up_bdec_[2] = {(const float*)d_in[10], (const float*)d_in[14]};
  const float* pf_[2]      = {(const float*)d_in[11], (const float*)d_in[15]};
  const float* mask_[2]    = {(const float*)d_in[12], (const float*)d_in[16]};

  float* out_feat  = (float*)d_out;
  float* out_recon = out_feat + (size_t)B * S * F;

  // ---- workspace layout: 185.6 MB total (< 191.9 MB proven in round 2) ----
  float* ws = (float*)d_ws;
  size_t o = 0;
  float* P     = ws + o; o += (size_t)B * S * F;          // 25.2 MB
  float* bias0 = ws + o; o += F;
  float* evec  = ws + o; o += F;
  float* cvec  = ws + o; o += D;
  float* ctmp  = ws + o; o += (size_t)H * D;
  float* topv  = ws + o; o += (size_t)B * S * TOPK;
  int*   topi  = (int*)(ws + o); o += (size_t)B * S * TOPK;
  u16* encwPh = (u16*)(ws + o); o += (size_t)F * D / 2;
  u16* encwPl = (u16*)(ws + o); o += (size_t)F * D / 2;
  u16* wovPh  = (u16*)(ws + o); o += (size_t)H * D * D / 2;
  u16* wovPl  = (u16*)(ws + o); o += (size_t)H * D * D / 2;
  u16* udTh   = (u16*)(ws + o); o += (size_t)2 * F * D / 2;   // [u][F][D]
  u16* udTl   = (u16*)(ws + o); o += (size_t)2 * F * D / 2;
  u16* actTh  = (u16*)(ws + o); o += (size_t)B * D * S / 2;   // [b][D][S]
  u16* actTl  = (u16*)(ws + o); o += (size_t)B * D * S / 2;
  u16* Gh     = (u16*)(ws + o); o += (size_t)2 * B * F * S / 2;  // [u][b][F][S]
  u16* Gl     = (u16*)(ws + o); o += (size_t)2 * B * F * S / 2;
  u16* Phh    = (u16*)(ws + o); o += (size_t)B * S * S / 2;   // per-h probs pair
  u16* Phl    = (u16*)(ws + o); o += (size_t)B * S * S / 2;
  u16* Ehh    = (u16*)(ws + o); o += (size_t)F * 512 / 2;     // per-h Eh pair
  u16* Ehl    = (u16*)(ws + o); o += (size_t)F * 512 / 2;
  const size_t xoff = o;                                      // dec_wT alias
  u16* Xh     = (u16*)(ws + o); o += (size_t)B * S * 3072 / 2;  // per-h X pair
  u16* Xl     = (u16*)(ws + o); o += (size_t)B * S * 3072 / 2;
  u16* vwh    = (u16*)(ws + o); o += (size_t)F * 3072 / 2;    // per-(h,u) vw pair
  u16* vwl    = (u16*)(ws + o); o += (size_t)F * 3072 / 2;
  float* dec_wT = ws + xoff;  // used only after h-loop (X region dead by then)

  hipMemsetAsync(out_feat, 0, sizeof(float) * (size_t)B * S * F, stream);
  hipMemsetAsync(P, 0, sizeof(float) * (size_t)B * S * F, stream);

  // ---- operand prep ----
  split_pair<<<1024, 256, 0, stream>>>(enc_w, encwPh, encwPl, (long)F * D);
  split_pair<<<1024, 256, 0, stream>>>(W_OV, wovPh, wovPl, (long)H * D * D);
  for (int b = 0; b < B; ++b)
    transpose_split<<<dim3(D / 32, S / 32), 256, 0, stream>>>(
        resid + (size_t)b * S * D, ln + (size_t)b * S,
        actTh + (size_t)b * D * S, actTl + (size_t)b * D * S, S, D);
  for (int u = 0; u < 2; ++u) {
    for (int b = 0; b < B; ++b)
      transpose_split<<<dim3(F / 32, S / 32), 256, 0, stream>>>(
          pf_[u] + (size_t)b * S * F, ln + (size_t)b * S,
          Gh + ((size_t)u * B + b) * F * S, Gl + ((size_t)u * B + b) * F * S,
          S, F);
    transpose_split<<<dim3(F / 32, D / 32), 256, 0, stream>>>(
        up_dec_[u], nullptr, udTh + (size_t)u * F * D, udTl + (size_t)u * F * D,
        D, F);
  }
  cvec_partial<<<dim3(2, 8), 256, 0, stream>>>(W_OV, up_bdec_[0], up_bdec_[1], ctmp);
  cvec_reduce<<<2, 256, 0, stream>>>(ctmp, cvec);
  bias_vec<<<F, 64, 0, stream>>>(enc_w, b_O, b_dec, enc_b, cvec, bias0, evec);

  // ---- per-head pipeline ----
  for (int h = 0; h < H; ++h) {
    // probs[:,h] split pair
    for (int b = 0; b < B; ++b)
      split_pair<<<512, 256, 0, stream>>>(
          probs + ((size_t)b * H + h) * S * S,
          Phh + (size_t)b * S * S, Phl + (size_t)b * S * S, (long)S * S);
    // Eh[f,i] = sum_o enc_w[f,o] * W_OV[h,i,o] -> pair [F][512]
    gemm_split3<false, false, false, true><<<96, 256, 0, stream>>>(
        encwPh, encwPl, wovPh + (size_t)h * D * D, wovPl + (size_t)h * D * D,
        nullptr, Ehh, Ehl, nullptr, nullptr, 0,
        512, 512, 512, 512, 4, 24, 1, 0L, 0L, 0L, 0L, 0L, 0L);
    // Xact[b][q][d] = probs_h[b] @ actT[b]^T (causal) -> pair, ldc=512
    gemm_split3<false, true, false, true><<<64, 256, 0, stream>>>(
        Phh, Phl, actTh, actTl, nullptr, Xh, Xl, nullptr, nullptr, 0,
        S, S, S, 512, 4, 8, 2,
        (long)S * S, 0L, (long)D * S, 0L, (long)S * 512, 0L);
    // P[b] += Xact[b] @ Eh^T  (K=512)
    gemm_split3<true, false, false, false><<<384, 256, 0, stream>>>(
        Xh, Xl, Ehh, Ehl, P, nullptr, nullptr, nullptr, nullptr, 0,
        512, 512, 512, F, 24, 8, 2,
        (long)S * 512, 0L, 0L, 0L, (long)S * F, 0L);

    for (int u = 0; u < 2; ++u) {
      // X[b][q][n] = probs_h[b] @ G_u[b]^T (causal) -> pair, ldc=3072
      gemm_split3<false, true, false, true><<<384, 256, 0, stream>>>(
          Phh, Phl, Gh + (size_t)u * B * F * S, Gl + (size_t)u * B * F * S,
          nullptr, Xh, Xl, nullptr, nullptr, 0,
          S, S, S, 3072, 24, 8, 2,
          (long)S * S, 0L, (long)F * S, 0L, (long)S * 3072, 0L);
      // vw[d][n] = (Eh @ udT_u^T)[d][n] * mask_u[d][n] -> pair [F][3072]
      gemm_split3<false, false, true, true><<<576, 256, 0, stream>>>(
          Ehh, Ehl, udTh + (size_t)u * F * D, udTl + (size_t)u * F * D,
          nullptr, vwh, vwl, mask_[u], nullptr, F,
          512, 512, 512, 3072, 24, 24, 1, 0L, 0L, 0L, 0L, 0L, 0L);
      // P[b] += X[b] @ vw^T  (K=3072)
      gemm_split3<true, false, false, false><<<384, 256, 0, stream>>>(
          Xh, Xl, vwh, vwl, P, nullptr, nullptr, nullptr, nullptr, 0,
          3072, 3072, 3072, F, 24, 8, 2,
          (long)S * 3072, 0L, 0L, 0L, (long)S * F, 0L);
    }
  }

  // ---- tail: dec_w transpose (into dead X region), topk, recon ----
  transpose_dw<<<dim3(F / 32, D / 32), 256, 0, stream>>>(dec_w, dec_wT);
  topk_fused<<<B * S, 256, 0, stream>>>(P, bias0, evec, ln, out_feat, topv, topi);
  recon_kernel<<<B * S, 256, 0, stream>>>(topv, topi, dec_wT, b_dec, out_recon);
}